// Round 1
// baseline (148.801 us; speedup 1.0000x reference)
//
#include <hip/hip_runtime.h>

// Reference-exact fp32 d2: no FMA contraction. d2 = (sqn+sqm) + dot' with
// dot' built from (-2x) pre-scaled m-points is bit-identical to the ref's
// (sqn+sqm) - 2*dot (power-of-2 scaling / negation commute with rounding).
// Self-distance: dt(n,n) = -2*sq_n exactly, so d2(n,n) == 0 exactly.
#pragma clang fp contract(off)

#define NBATCH 256   // B*L
#define NPTS   512   // points per batch
#define JDIM   128   // logit dim
#define NPAIR  (NBATCH * NPTS)   // 131072
#define NCHUNK 8     // j-chunks of 16 rows
#define ROWS   16

// ---------------- Fused kernel: one block per batch --------------------------
// 256 blocks x 512 threads. Thread t owns point t end-to-end:
//   Phase A: argmax / masked-argmin of d2 over all 512 m (indices stay in regs;
//            no cross-thread merge, no pmax/pmin global round-trip).
//   Phase B: 8 j-chunks of ypred streamed through 2 LDS tiles with 3-deep
//            register prefetch; per-chunk partial replicates old K2 bit-exact.
// The 12 prologue float4 loads (chunks 0-2, 96 KB/CU) are issued BEFORE
// phase A so HBM streams under the ~12us of VALU work.
__global__ __launch_bounds__(512) void fused_kernel(
    const float* __restrict__ ypred,   // [NBATCH, JDIM, NPTS]
    const float* __restrict__ xyz,     // [NBATCH, NPTS, 3]
    float* __restrict__ partials)      // [NBATCH*NCHUNK] = [2048]
{
    __shared__ float4 xyzS[NPTS];                         // 8 KB
    __shared__ __align__(16) float Lt[2][ROWS * NPTS];    // 64 KB
    __shared__ float wredc[NCHUNK][8];                    // 256 B

    const int t  = threadIdx.x;
    const int bl = blockIdx.x;
    const float*  xp  = xyz + (size_t)bl * NPTS * 3;
    const float4* src = (const float4*)(ypred + (size_t)bl * JDIM * NPTS);

    // ---- issue ypred prefetch for chunks 0..2 first; lands during phase A ----
    float4 r0[4], r1[4], r2[4];
    #pragma unroll
    for (int q = 0; q < 4; ++q) r0[q] = src[0 * 2048 + q * 512 + t];
    #pragma unroll
    for (int q = 0; q < 4; ++q) r1[q] = src[1 * 2048 + q * 512 + t];
    #pragma unroll
    for (int q = 0; q < 4; ++q) r2[q] = src[2 * 2048 + q * 512 + t];

    // ---- stage scaled points + keep own point raw in regs ----
    float ox = xp[3 * t], oy = xp[3 * t + 1], oz = xp[3 * t + 2];
    float oq = (ox * ox + oy * oy) + oz * oz;   // matches np.sum(x*x,-1) order
    xyzS[t] = make_float4(-2.0f * ox, -2.0f * oy, -2.0f * oz, oq);
    __syncthreads();

    // ---- Phase A: scan all 512 m, ascending, strict compares ----
    // First-occurrence semantics identical to the split K1+merge: bmax starts
    // at -1 (any d2 > -1, so m=0 always seeds), min candidates require d2>0
    // (folds the ref's clamp(d2)==0 self/dupe mask into the compare).
    float bmax = -1.0f, bmin = 3.0e38f;
    int   ima  = 0,     imi  = 0;
    #pragma unroll 8
    for (int m = 0; m < NPTS; ++m) {
        float4 qv = xyzS[m];                 // wave-uniform -> broadcast read
        float dt = (ox * qv.x + oy * qv.y) + oz * qv.z;   // == -2*dot, exact
        float d2 = (oq + qv.w) + dt;         // bits == ref d2 (pre-clamp)
        bool gt = d2 > bmax;                 // strict -> first occurrence
        ima = gt ? m : ima;  bmax = gt ? d2 : bmax;
        bool lt = (d2 < bmin) && (d2 > 0.0f);
        imi = lt ? m : imi;  bmin = lt ? d2 : bmin;
    }
    const int pma = ima, pmi = imi;          // partner columns, in registers

    // ---- Phase B prologue: tile0 <- chunk0 (waits only r0: counted vmcnt) ----
    {
        float4* dst = (float4*)Lt[0];
        #pragma unroll
        for (int q = 0; q < 4; ++q) dst[q * 512 + t] = r0[q];
    }
    __syncthreads();

#define PREFETCH(cc, R)                                                        \
    { _Pragma("unroll")                                                        \
      for (int q = 0; q < 4; ++q) R[q] = src[(cc) * 2048 + q * 512 + t]; }
#define DSWRITE(cc, R)                                                         \
    { float4* dst = (float4*)Lt[(cc) & 1];                                     \
      _Pragma("unroll")                                                        \
      for (int q = 0; q < 4; ++q) dst[q * 512 + t] = R[q]; }

    // ---- Phase B: chunk c in tile[c&1]; reg set c%3 holds chunk c ----
    #pragma unroll
    for (int c = 0; c < NCHUNK; ++c) {
        // 1) refill the set freed last iter with chunk c+3 (issue early)
        if (c + 3 < NCHUNK) {
            if (c % 3 == 0)      PREFETCH(c + 3, r0)
            else if (c % 3 == 1) PREFETCH(c + 3, r1)
            else                 PREFETCH(c + 3, r2)
        }
        // 2) stage chunk c+1 into the other tile (its loads landed ~1 chunk ago)
        if (c + 1 < NCHUNK) {
            if ((c + 1) % 3 == 0)      DSWRITE(c + 1, r0)
            else if ((c + 1) % 3 == 1) DSWRITE(c + 1, r1)
            else                       DSWRITE(c + 1, r2)
        }
        // 3) compute chunk c — bit-exact replica of old K2's per-chunk path
        const float* L = Lt[c & 1];
        float accP = 0.0f, accM = 0.0f;
        #pragma unroll
        for (int r = 0; r < ROWS; ++r) {
            float a  = L[r * NPTS + t];      // stride-1, conflict-free
            float b  = L[r * NPTS + pma];    // random gather, ~2-way (free)
            float cm = L[r * NPTS + pmi];
            accP = fmaf(a, b, accP);
            accM = fmaf(a, cm, accM);
        }
        float d = accP - accM;
        #pragma unroll
        for (int off = 32; off > 0; off >>= 1)
            d += __shfl_down(d, off);
        if ((t & 63) == 0) wredc[c][t >> 6] = d;
        __syncthreads();                     // tile c+1 ready AND wredc[c] ready
        if (t == 0) {
            float ssum = 0.0f;
            #pragma unroll
            for (int w = 0; w < 8; ++w) ssum += wredc[c][w];
            partials[bl * NCHUNK + c] = ssum;   // same values as old K2
        }
    }
#undef PREFETCH
#undef DSWRITE
}

// ---------------- K3: final mean over 2048 partials (unchanged) -------------
__global__ __launch_bounds__(1024) void reduce_mean_kernel(
    const float* __restrict__ partials, float* __restrict__ out)
{
    const int t = threadIdx.x;
    float v = partials[t] + partials[t + 1024];
    #pragma unroll
    for (int off = 32; off > 0; off >>= 1)
        v += __shfl_down(v, off);

    __shared__ float w[16];
    if ((t & 63) == 0) w[t >> 6] = v;
    __syncthreads();
    if (t == 0) {
        float s = 0.0f;
        #pragma unroll
        for (int i = 0; i < 16; ++i) s += w[i];
        out[0] = s * (1.0f / (float)NPAIR);
    }
}

extern "C" void kernel_launch(void* const* d_in, const int* in_sizes, int n_in,
                              void* d_out, int out_size, void* d_ws, size_t ws_size,
                              hipStream_t stream) {
    const float* ypred = (const float*)d_in[0];   // [8,32,128,512] f32
    const float* xyz   = (const float*)d_in[1];   // [8,32,512,3]  f32

    // ws: partials[2048] floats only (indices never leave registers now)
    float* partials = (float*)d_ws;
    float* out      = (float*)d_out;

    fused_kernel<<<NBATCH, 512, 0, stream>>>(ypred, xyz, partials);
    reduce_mean_kernel<<<1, 1024, 0, stream>>>(partials, out);
}

// Round 2
// 129.126 us; speedup vs baseline: 1.1524x; 1.1524x over previous
//
#include <hip/hip_runtime.h>

// Reference-exact fp32 d2: no FMA contraction. d2 = (sqn+sqm) + dot' with
// dot' built from (-2x) pre-scaled m-points is bit-identical to the ref's
// (sqn+sqm) - 2*dot (power-of-2 scaling / negation commute with rounding).
// Self-distance: dt(n,n) = -2*sq_n exactly, so d2(n,n) == 0 exactly.
#pragma clang fp contract(off)

#define NBATCH 256   // B*L
#define NPTS   512   // points per batch
#define JDIM   128   // logit dim
#define NPAIR  (NBATCH * NPTS)   // 131072
#define NCHUNK 8     // j-chunks of 16 rows
#define ROWS   16

// Direct HBM->LDS DMA, 16B per lane. LDS dest must be wave-uniform base;
// lane l lands at base + l*16. Our tile layout tile[q*512 + t] (float4) is
// exactly that order for base = tile + q*512 + (t & ~63).
__device__ __forceinline__ void gload_lds16(const void* g, void* l) {
    __builtin_amdgcn_global_load_lds(
        (const __attribute__((address_space(1))) void*)g,
        (__attribute__((address_space(3))) void*)l, 16, 0, 0);
}

// ---------------- Fused kernel: one block per batch --------------------------
// 256 blocks x 512 threads; thread t owns point t end-to-end.
//   Phase A: argmax / masked-argmin of d2 over all 512 m (indices stay in regs).
//   Phase B: 8 j-chunks of ypred streamed through 3 LDS tiles via
//            global_load_lds (zero VGPR cost -> no spills), raw s_barrier +
//            counted vmcnt keeps 2 chunks in flight across barriers.
// Chunks 0..2 are issued BEFORE phase A so ~96 KB/CU of ypred streams in
// under phase A's ~12us of VALU work.
__global__ __launch_bounds__(512) void fused_kernel(
    const float* __restrict__ ypred,   // [NBATCH, JDIM, NPTS]
    const float* __restrict__ xyz,     // [NBATCH, NPTS, 3]
    float* __restrict__ partials)      // [NBATCH*NCHUNK] = [2048]
{
    __shared__ float4 xyzS[NPTS];                         //  8 KB
    __shared__ __align__(16) float Lt[3][ROWS * NPTS];    // 96 KB
    __shared__ float wredc[NCHUNK][8];                    // 256 B

    const int t  = threadIdx.x;
    const int bl = blockIdx.x;
    const float*  xp  = xyz + (size_t)bl * NPTS * 3;
    const float4* src = (const float4*)(ypred + (size_t)bl * JDIM * NPTS);
    const int wbase = t & ~63;        // wave-uniform lane base for DMA dest

    // ---- own point: load + stage scaled form (consume xyz before DMA issue) --
    float ox = xp[3 * t], oy = xp[3 * t + 1], oz = xp[3 * t + 2];
    float oq = (ox * ox + oy * oy) + oz * oz;   // matches np.sum(x*x,-1) order
    xyzS[t] = make_float4(-2.0f * ox, -2.0f * oy, -2.0f * oz, oq);

    // ---- issue async staging of chunks 0..2 (12 loads/wave in flight) -------
    #pragma unroll
    for (int c0 = 0; c0 < 3; ++c0) {
        float4* tile = (float4*)Lt[c0];
        #pragma unroll
        for (int q = 0; q < 4; ++q)
            gload_lds16(src + c0 * 2048 + q * 512 + t, tile + q * 512 + wbase);
    }

    // xyzS visible to all waves; do NOT drain vmcnt (raw barrier, lgkm only)
    asm volatile("s_waitcnt lgkmcnt(0)" ::: "memory");
    __builtin_amdgcn_s_barrier();

    // ---- Phase A: scan all 512 m, ascending, strict compares ----------------
    // First-occurrence semantics identical to the verified split K1+merge:
    // bmax seeds at -1 (m=0 always wins first), min candidates require d2>0
    // (folds the ref's clamp(d2)==0 self/dupe mask into the compare).
    float bmax = -1.0f, bmin = 3.0e38f;
    int   ima  = 0,     imi  = 0;
    #pragma unroll 8
    for (int m = 0; m < NPTS; ++m) {
        float4 qv = xyzS[m];                 // wave-uniform -> broadcast read
        float dt = (ox * qv.x + oy * qv.y) + oz * qv.z;   // == -2*dot, exact
        float d2 = (oq + qv.w) + dt;         // bits == ref d2 (pre-clamp)
        bool gt = d2 > bmax;                 // strict -> first occurrence
        ima = gt ? m : ima;  bmax = gt ? d2 : bmax;
        bool lt = (d2 < bmin) && (d2 > 0.0f);
        imi = lt ? m : imi;  bmin = lt ? d2 : bmin;
    }
    const int pma = ima, pmi = imi;          // partner columns, in registers

    // ---- Phase B: chunk c lives in tile[c%3]; 2 chunks always in flight -----
    #pragma unroll
    for (int c = 0; c < NCHUNK; ++c) {
        // wait until chunk c's DMA landed (counted: never drain in main loop).
        // Outstanding after wait = the newest 8 loads = chunks c+1, c+2.
        if (c <= 5)      asm volatile("s_waitcnt vmcnt(8)" ::: "memory");
        else if (c == 6) asm volatile("s_waitcnt vmcnt(4)" ::: "memory");
        else             asm volatile("s_waitcnt vmcnt(0)" ::: "memory");
        __builtin_amdgcn_s_barrier();        // all waves' chunk-c loads landed

        // compute chunk c — bit-exact replica of old K2's per-chunk path
        const float* L = Lt[c % 3];
        float accP = 0.0f, accM = 0.0f;
        #pragma unroll
        for (int r = 0; r < ROWS; ++r) {
            float a  = L[r * NPTS + t];      // stride-1, conflict-free
            float b  = L[r * NPTS + pma];    // random gather, ~2-way (free)
            float cm = L[r * NPTS + pmi];
            accP = fmaf(a, b, accP);
            accM = fmaf(a, cm, accM);
        }
        float d = accP - accM;
        #pragma unroll
        for (int off = 32; off > 0; off >>= 1)
            d += __shfl_down(d, off);
        if ((t & 63) == 0) wredc[c][t >> 6] = d;   // deferred; read after loop

        if (c + 3 < NCHUNK) {
            // every wave has consumed its tile[c%3] reads (fmas executed) ->
            // after this barrier the tile is safe to overwrite via DMA.
            __builtin_amdgcn_s_barrier();
            float4* tile = (float4*)Lt[c % 3];
            #pragma unroll
            for (int q = 0; q < 4; ++q)
                gload_lds16(src + (c + 3) * 2048 + q * 512 + t,
                            tile + q * 512 + wbase);
        }
    }

    // ---- fold the 8 chunk partials (same w=0..7 order as old K2 -> same bits)
    asm volatile("s_waitcnt lgkmcnt(0)" ::: "memory");
    __builtin_amdgcn_s_barrier();
    if (t < NCHUNK) {
        float ssum = 0.0f;
        #pragma unroll
        for (int w = 0; w < 8; ++w) ssum += wredc[t][w];
        partials[bl * NCHUNK + t] = ssum;
    }
}

// ---------------- K3: final mean over 2048 partials (unchanged) -------------
__global__ __launch_bounds__(1024) void reduce_mean_kernel(
    const float* __restrict__ partials, float* __restrict__ out)
{
    const int t = threadIdx.x;
    float v = partials[t] + partials[t + 1024];
    #pragma unroll
    for (int off = 32; off > 0; off >>= 1)
        v += __shfl_down(v, off);

    __shared__ float w[16];
    if ((t & 63) == 0) w[t >> 6] = v;
    __syncthreads();
    if (t == 0) {
        float s = 0.0f;
        #pragma unroll
        for (int i = 0; i < 16; ++i) s += w[i];
        out[0] = s * (1.0f / (float)NPAIR);
    }
}

extern "C" void kernel_launch(void* const* d_in, const int* in_sizes, int n_in,
                              void* d_out, int out_size, void* d_ws, size_t ws_size,
                              hipStream_t stream) {
    const float* ypred = (const float*)d_in[0];   // [8,32,128,512] f32
    const float* xyz   = (const float*)d_in[1];   // [8,32,512,3]  f32

    // ws: partials[2048] floats only (indices never leave registers)
    float* partials = (float*)d_ws;
    float* out      = (float*)d_out;

    fused_kernel<<<NBATCH, 512, 0, stream>>>(ypred, xyz, partials);
    reduce_mean_kernel<<<1, 1024, 0, stream>>>(partials, out);
}

// Round 4
// 121.231 us; speedup vs baseline: 1.2274x; 1.0651x over previous
//
#include <hip/hip_runtime.h>

// Reference-exact fp32 d2: no FMA contraction. d2 = (sqn+sqm) + dot' with
// dot' built from (-2x) pre-scaled m-points is bit-identical to the ref's
// (sqn+sqm) - 2*dot (power-of-2 scaling / negation commute with rounding).
// Self-distance: dt(n,n) = -2*sq_n exactly, so d2(n,n) == 0 exactly.
#pragma clang fp contract(off)

#define NBATCH 256   // B*L
#define NPTS   512   // points per batch
#define JDIM   128   // logit dim
#define NPAIR  (NBATCH * NPTS)   // 131072
#define NCHUNK 8     // j-chunks of 16 rows
#define ROWS   16

// Direct HBM->LDS DMA, 16B per lane. LDS dest is wave-uniform base; lane l
// lands at base + l*16. tile[q*512 + t] (float4) order == base + lane*16
// for base = tile + q*512 + (t & ~63).  (verified bit-exact in round 2)
__device__ __forceinline__ void gload_lds16(const void* g, void* l) {
    __builtin_amdgcn_global_load_lds(
        (const __attribute__((address_space(1))) void*)g,
        (__attribute__((address_space(3))) void*)l, 16, 0, 0);
}

// ---------------- Fused kernel: TWO blocks per batch -------------------------
// Grid 512 = 256 batches x 2 halves; 512 threads; LDS 76 KB -> exactly
// 2 blocks/CU resident (16 waves/CU), blocks fully independent (no 1-block
// convoy, no grid==CU fragility).
//   h = blockIdx>>8 so blocks b and b+256 (same batch) share b%8 -> same XCD
//   -> the batch's second ypred read hits that XCD's L2.
// Phase A: 2 threads per point (m-range split 0-255 / 256-511), strict-compare
//          LDS merge -> bit-identical first-occurrence indices.
// Phase B: all 8 chunks, double-buffered 32 KB tiles via global_load_lds,
//          1 barrier/chunk, vmcnt(0) depth-1 prefetch; waves 0-3 compute the
//          block's 256 points; per-wave sums go straight to partials2 in the
//          ORIGINAL wave order (w_global = h*4 + w) so K3's sequential fold
//          reproduces the old partials bit-for-bit.
__global__ __launch_bounds__(512) void fused_kernel(
    const float* __restrict__ ypred,     // [NBATCH, JDIM, NPTS]
    const float* __restrict__ xyz,       // [NBATCH, NPTS, 3]
    float* __restrict__ partials2)       // [NBATCH*NCHUNK][8] wave sums
{
    __shared__ float4 xyzS[NPTS];                         //  8 KB
    __shared__ __align__(16) float Lt[2][ROWS * NPTS];    // 64 KB
    __shared__ float mxv[256]; __shared__ int mxi[256];   //  2 KB
    __shared__ float mnv[256]; __shared__ int mni[256];   //  2 KB

    const int t  = threadIdx.x;
    const int bl = blockIdx.x & 255;     // batch
    const int h  = blockIdx.x >> 8;      // point-half: 0 or 1
    const float*  xp  = xyz + (size_t)bl * NPTS * 3;
    const float4* src = (const float4*)(ypred + (size_t)bl * JDIM * NPTS);
    const int wbase = t & ~63;           // wave-uniform DMA dest base

    // ---- stage all 512 scaled points ----
    {
        float x = xp[3 * t], y = xp[3 * t + 1], z = xp[3 * t + 2];
        float sq = (x * x + y * y) + z * z;   // matches np.sum(x*x,-1) order
        xyzS[t] = make_float4(-2.0f * x, -2.0f * y, -2.0f * z, sq);
    }

    // ---- own point: p = h*256 + (t&255); m-half mh = t>>8 ----
    const int p  = h * 256 + (t & 255);
    const int mh = t >> 8;
    float ox = xp[3 * p], oy = xp[3 * p + 1], oz = xp[3 * p + 2];
    float oq = (ox * ox + oy * oy) + oz * oz;

    // ---- issue chunk-0 DMA now; it streams in under phase A ----
    #pragma unroll
    for (int q = 0; q < 4; ++q)
        gload_lds16(src + q * 512 + t, (float4*)Lt[0] + q * 512 + wbase);

    // xyzS visible to all waves; keep the DMA in flight (lgkm-only barrier)
    asm volatile("s_waitcnt lgkmcnt(0)" ::: "memory");
    __builtin_amdgcn_s_barrier();

    // ---- Phase A: scan this thread's 256 m's, ascending, strict compares ----
    const int m0 = mh << 8;
    float bmax = -1.0f, bmin = 3.0e38f;
    int   ima  = m0,    imi  = m0;
    #pragma unroll 8
    for (int mm = 0; mm < 256; ++mm) {
        int m = m0 + mm;
        float4 qv = xyzS[m];                 // wave-uniform -> broadcast read
        float dt = (ox * qv.x + oy * qv.y) + oz * qv.z;   // == -2*dot, exact
        float d2 = (oq + qv.w) + dt;         // bits == ref d2 (pre-clamp)
        bool gt = d2 > bmax;                 // strict -> first occurrence
        ima = gt ? m : ima;  bmax = gt ? d2 : bmax;
        bool lt = (d2 < bmin) && (d2 > 0.0f);
        imi = lt ? m : imi;  bmin = lt ? d2 : bmin;
    }

    // ---- merge the two m-halves (strict: ties keep lower m-range == ref) ----
    if (t >= 256) {
        mxv[t - 256] = bmax;  mxi[t - 256] = ima;
        mnv[t - 256] = bmin;  mni[t - 256] = imi;
    }
    __syncthreads();          // drains vmcnt too; chunk 0 landed long ago
    int pma = ima, pmi = imi;
    if (t < 256) {
        float v1 = mxv[t];  if (v1 > bmax) pma = mxi[t];
        float u1 = mnv[t];  if (u1 < bmin) pmi = mni[t];
    }

    // ---- Phase B: chunk c in Lt[c&1]; issue c+1 right after the barrier ----
    for (int c = 0; c < NCHUNK; ++c) {
        // chunk c's DMA landed (c=0 already drained by __syncthreads above)
        asm volatile("s_waitcnt vmcnt(0)" ::: "memory");
        __builtin_amdgcn_s_barrier();    // + all waves done reading Lt[(c+1)&1]

        if (c + 1 < NCHUNK) {            // prefetch c+1 into the freed tile
            float4* tile = (float4*)Lt[(c + 1) & 1];
            #pragma unroll
            for (int q = 0; q < 4; ++q)
                gload_lds16(src + (c + 1) * 2048 + q * 512 + t,
                            tile + q * 512 + wbase);
        }

        if (t < 256) {                   // waves 0-3: this block's 256 points
            const float* L = Lt[c & 1];
            const int col = h * 256 + t;
            float accP = 0.0f, accM = 0.0f;
            #pragma unroll
            for (int r = 0; r < ROWS; ++r) {
                float a  = L[r * NPTS + col];   // stride-1, conflict-free
                float b  = L[r * NPTS + pma];   // random gather
                float cm = L[r * NPTS + pmi];
                accP = fmaf(a, b, accP);
                accM = fmaf(a, cm, accM);
            }
            float d = accP - accM;
            #pragma unroll
            for (int off = 32; off > 0; off >>= 1)
                d += __shfl_down(d, off);
            // global wave index = h*4 + local wave -> original wredc order
            if ((t & 63) == 0)
                partials2[(size_t)(bl * NCHUNK + c) * 8 + h * 4 + (t >> 6)] = d;
        }
    }
}

// ---------------- K3: fold wave sums exactly like the old pipeline ----------
// old partials[i] = sum_{w=0..7} wredc[w] sequential; then the old tree.
__global__ __launch_bounds__(1024) void reduce_mean_kernel(
    const float* __restrict__ partials2, float* __restrict__ out)
{
    const int t = threadIdx.x;
    const float4* p4 = (const float4*)partials2;

    float4 a0 = p4[2 * t],          a1 = p4[2 * t + 1];
    float4 b0 = p4[2 * (t + 1024)], b1 = p4[2 * (t + 1024) + 1];
    float fa = ((((((a0.x + a0.y) + a0.z) + a0.w) + a1.x) + a1.y) + a1.z) + a1.w;
    float fb = ((((((b0.x + b0.y) + b0.z) + b0.w) + b1.x) + b1.y) + b1.z) + b1.w;
    float v = fa + fb;               // == old partials[t] + partials[t+1024]

    #pragma unroll
    for (int off = 32; off > 0; off >>= 1)
        v += __shfl_down(v, off);

    __shared__ float w[16];
    if ((t & 63) == 0) w[t >> 6] = v;
    __syncthreads();
    if (t == 0) {
        float s = 0.0f;
        #pragma unroll
        for (int i = 0; i < 16; ++i) s += w[i];
        out[0] = s * (1.0f / (float)NPAIR);
    }
}

extern "C" void kernel_launch(void* const* d_in, const int* in_sizes, int n_in,
                              void* d_out, int out_size, void* d_ws, size_t ws_size,
                              hipStream_t stream) {
    const float* ypred = (const float*)d_in[0];   // [8,32,128,512] f32
    const float* xyz   = (const float*)d_in[1];   // [8,32,512,3]  f32

    // ws: partials2[2048*8] floats = 64 KB (every slot written each launch)
    float* partials2 = (float*)d_ws;
    float* out       = (float*)d_out;

    fused_kernel<<<2 * NBATCH, 512, 0, stream>>>(ypred, xyz, partials2);
    reduce_mean_kernel<<<1, 1024, 0, stream>>>(partials2, out);
}